// Round 15
// baseline (533.707 us; speedup 1.0000x reference)
//
#include <hip/hip_runtime.h>
#include <math.h>

// ---------------- workspace layout (float2 units) ----------------
// ws_bs : 24 gates x 384  sector-packed BS: for sector N (size s, row SR=even(s)),
//                         g[SECBASE[N] + o*SR + ti] = U[j_o][k_ti]
// ws_g1 : 16 gates x 64   one-mode GT[k*8+j] with rotation/Kerr diagonals folded
#define WS_G1_OFF   (24*384)

typedef float v2f __attribute__((ext_vector_type(2)));
typedef float v4f __attribute__((ext_vector_type(4)));

// complex MAC, gate in SGPR pair: 2 VALU per cmac, zero movs.
__device__ __forceinline__ void cmac_s(v2f& acc, v2f s, v2f g){
  asm("v_pk_fma_f32 %0, %1, %2, %0 op_sel_hi:[0,1,1]\n\t"
      "v_pk_fma_f32 %0, %1, %2, %0 op_sel:[1,1,0] op_sel_hi:[1,0,1] neg_lo:[1,0,0]"
      : "+v"(acc) : "v"(s), "s"(g));
}
// acc = s*g with inline-0 src2 on the first pk (no v_mov init)
__device__ __forceinline__ v2f cmul_s0(v2f s, v2f g){
  v2f acc;
  asm("v_pk_fma_f32 %0, %1, %2, 0 op_sel_hi:[0,1,1]\n\t"
      "v_pk_fma_f32 %0, %1, %2, %0 op_sel:[1,1,0] op_sel_hi:[1,0,1] neg_lo:[1,0,0]"
      : "=&v"(acc) : "v"(s), "s"(g));
  return acc;
}
// all-VGPR variant for setup kernels (operands not provably uniform)
__device__ __forceinline__ void cmac_v(v2f& acc, v2f s, v2f g){
  asm("v_pk_fma_f32 %0, %1, %2, %0 op_sel_hi:[0,1,1]\n\t"
      "v_pk_fma_f32 %0, %1, %2, %0 op_sel:[1,1,0] op_sel_hi:[1,0,1] neg_lo:[1,0,0]"
      : "+v"(acc) : "v"(s), "v"(g));
}

// ---------------- setup: 24 beamsplitter 64x64 expm ----------------
__global__ __launch_bounds__(256) void setup_bs(
    const float* __restrict__ th1, const float* __restrict__ ph1,
    const float* __restrict__ th2, const float* __restrict__ ph2,
    float2* __restrict__ ws)
{
  __shared__ float2 bufA[4096];
  __shared__ float2 bufB[4096];
  const int g = blockIdx.x;          // 0..23
  const int t = threadIdx.x;
  const int l = g/12, intf = (g%12)/6, pos = g%6;
  const float th = (intf ? th2 : th1)[l*6+pos];
  const float ph = (intf ? ph2 : ph1)[l*6+pos];
  float nrm = fabsf(th)*14.0f;                 // row-sum norm bound
  int sq = 0;
  if (nrm > 2.0f) sq = (int)ceilf(log2f(nrm*0.5f));   // Taylor-12 good to ||H||<=2
  const float tc  = th * ldexpf(1.0f, -sq);    // scaled theta
  const float cph = cosf(ph), sph = sinf(ph);

  float2* cur = bufA; float2* nxt = bufB;
  for (int e=0;e<16;e++){ int idx=e*256+t;
    cur[idx] = make_float2(((idx>>6)==(idx&63))?1.f:0.f, 0.f); }
  __syncthreads();
  // Horner Taylor: B = I + Hs*B/k, k=12..1   (Hs applied sparsely: 2 taps/row)
  for (int k=12;k>=1;k--){
    const float inv = 1.0f/(float)k;
    for (int e=0;e<16;e++){
      const int idx=e*256+t; const int row=idx>>6, c=idx&63;
      const int m1=row>>3, m2=row&7;
      float vx=0.f, vy=0.f;
      if (m1<7 && m2>=1){
        const float mag = tc*sqrtf((float)((m1+1)*m2));
        const float2 q = cur[((m1+1)*8+(m2-1))*64 + c];
        vx += mag*(cph*q.x - sph*q.y);
        vy += mag*(cph*q.y + sph*q.x);
      }
      if (m1>=1 && m2<7){
        const float mag = tc*sqrtf((float)(m1*(m2+1)));
        const float2 q = cur[((m1-1)*8+(m2+1))*64 + c];
        vx -= mag*(cph*q.x + sph*q.y);
        vy -= mag*(cph*q.y - sph*q.x);
      }
      vx *= inv; vy *= inv;
      if (row==c) vx += 1.0f;
      nxt[idx] = make_float2(vx,vy);
    }
    __syncthreads();
    float2* tmp=cur; cur=nxt; nxt=tmp;
  }
  // squarings: pk_fma pairs, broadcast A row, conflict-free B column
  for (int si=0; si<sq; si++){
    for (int e=0;e<16;e++){
      const int idx=e*256+t; const int row=idx>>6, c=idx&63;
      const float2* Arow = cur + row*64;
      v2f acc = (v2f){0.f,0.f};
      for (int q=0;q<64;q+=2){
        const v4f ap = *(const v4f*)&Arow[q];
        const v2f b0 = *(const v2f*)&cur[q*64+c];
        const v2f b1 = *(const v2f*)&cur[(q+1)*64+c];
        cmac_v(acc, b0, (v2f){ap.x,ap.y});
        cmac_v(acc, b1, (v2f){ap.z,ap.w});
      }
      nxt[idx] = make_float2(acc.x, acc.y);
    }
    __syncthreads();
    float2* tmp=cur; cur=nxt; nxt=tmp;
  }
  // sector-packed write: enumerate (N, o, ti-with-row-pad) linearly over 384 slots
  for (int e=t; e<384; e+=256){
    int rem = e, N = 0, S_=0, SR_=0;
    for (; N<15; N++){
      S_  = 8 - ((N<7)?(7-N):(N-7));
      SR_ = (S_+1)&~1;
      if (rem < S_*SR_) break;
      rem -= S_*SR_;
    }
    float2 v = make_float2(0.f,0.f);
    if (N < 15){
      const int o = rem / SR_, ti = rem % SR_;
      if (ti < S_){
        const int T0 = (N>7)?(N-7):0;
        const int j = 7*(T0+o)+N, k = 7*(T0+ti)+N;
        v = cur[j*64 + k];
      }
    }
    ws[g*384 + e] = v;
  }
}

// ---------------- setup: 16 one-mode 8x8 expm, diagonals folded in ----------------
__global__ __launch_bounds__(128) void setup_small(
    const float* __restrict__ rr,  const float* __restrict__ phr,
    const float* __restrict__ aa,  const float* __restrict__ pha,
    const float* __restrict__ vph1,const float* __restrict__ vph2,
    const float* __restrict__ kap,
    float2* __restrict__ ws_g1)
{
  const int g = blockIdx.x, t = threadIdx.x;   // g: 0..15
  __shared__ float2 h8[64], bufA[64], bufB[64];
  const int isSq = (g < 8);
  const int gi = isSq ? g : (g-8);
  const int li = gi>>2, m = gi&3;
  const float p1 = isSq ? rr[li*4+m]  : aa[li*4+m];
  const float p2 = isSq ? phr[li*4+m] : pha[li*4+m];
  const float nrm = fabsf(p1)*6.0f;
  int sq = 0; if (nrm > 2.0f) sq = (int)ceilf(log2f(nrm*0.5f));
  const float sc = ldexpf(1.0f,-sq);
  const float cp = cosf(p2), sp = sinf(p2);
  if (t < 64){
    const int row=t>>3, c=t&7;
    float2 v = make_float2(0.f,0.f);
    if (isSq){
      if (c == row+2){ const float mg = 0.5f*p1*sqrtf((float)((row+1)*(row+2)));
                       v = make_float2( mg*cp, -mg*sp); }
      else if (c+2 == row){ const float mg = 0.5f*p1*sqrtf((float)((row-1)*row));
                       v = make_float2(-mg*cp, -mg*sp); }
    } else {
      if (c+1 == row){ const float mg = p1*sqrtf((float)row);
                       v = make_float2( mg*cp,  mg*sp); }
      else if (c == row+1){ const float mg = p1*sqrtf((float)(row+1));
                       v = make_float2(-mg*cp,  mg*sp); }
    }
    h8[t]   = make_float2(v.x*sc, v.y*sc);
    bufA[t] = make_float2((row==c)?1.f:0.f, 0.f);
  }
  __syncthreads();
  float2* cur=bufA; float2* nxt=bufB;
  for (int k=12;k>=1;k--){
    const float inv = 1.0f/(float)k;
    if (t<64){
      const int row=t>>3, c=t&7;
      float vx=0.f, vy=0.f;
      for (int q=0;q<8;q++){
        const float2 a_=h8[row*8+q], b_=cur[q*8+c];
        vx += a_.x*b_.x - a_.y*b_.y; vy += a_.x*b_.y + a_.y*b_.x;
      }
      vx*=inv; vy*=inv; if (row==c) vx += 1.f;
      nxt[t]=make_float2(vx,vy);
    }
    __syncthreads();
    float2* tmp=cur; cur=nxt; nxt=tmp;
  }
  for (int si=0; si<sq; si++){
    if (t<64){
      const int row=t>>3, c=t&7;
      float vx=0.f, vy=0.f;
      for (int q=0;q<8;q++){
        const float2 a_=cur[row*8+q], b_=cur[q*8+c];
        vx += a_.x*b_.x - a_.y*b_.y; vy += a_.x*b_.y + a_.y*b_.x;
      }
      nxt[t]=make_float2(vx,vy);
    }
    __syncthreads();
    float2* tmp=cur; cur=nxt; nxt=tmp;
  }
  if (t<64){
    const int kk=t>>3, j=t&7;
    const float2 v = cur[j*8+kk];          // G[j][kk]
    float ang;
    if (isSq) ang = vph1[li*4+m]*(float)kk;
    else      ang = vph2[li*4+m]*(float)kk + kap[li*4+m]*(float)(j*j);
    const float ca = cosf(ang), sa = sinf(ang);
    ws_g1[g*64 + t] = make_float2(v.x*ca - v.y*sa, v.x*sa + v.y*ca);  // GT[k][j]
  }
}

// ---------------- main kernel: 512 threads (8 waves), 4 blocks/CU ----------------
// State in LDS, padded: addr(idx) = idx + (idx>>6) -> strides i0:520 i1:65 i2:8 i3:1.
// LDS total 33792 B -> exactly 4 blocks/CU (5 blocks/CU triggers phantom HBM
// traffic: R3/R10/R13 all dirty at 5 blocks; every 4- or 2-block build clean).
// bs_gate (balanced): phase A = read taps into regs, barrier, phase B = compute
// assigned (sector, output-range) units, write, barrier. Balanced bins:
// 44/44/43/43/43/43/43/41 cmacs/wave (was 64/50/50/40/40/34/34/32).
// Gates: uniform s_load -> SGPR pair folded into v_pk_fma (2 VALU/cmac).

// padded tap offset for combined pair index k within each pair map
template<int PM>
__device__ __forceinline__ constexpr int koff(int k){
  return (PM==0) ? 65*k : ((PM==1) ? (8*k + (k>>3)) : k);
}

template<int NN,int PM>
__device__ __forceinline__ void bs_read(const float2* __restrict__ Sm, int sb,
                                        v2f* tap)
{
  constexpr int S_ = 8 - ((NN<7)?(7-NN):(NN-7));
  constexpr int T0 = (NN>7)?(NN-7):0;
#pragma unroll
  for (int i=0;i<S_;i++)
    tap[i] = *(const v2f*)&Sm[sb + koff<PM>(7*(T0+i)+NN)];   // offset:imm
}

template<int NN,int PM,int O0,int O1>
__device__ __forceinline__ void bs_comp(const float2* __restrict__ gsec,
                                        float2* __restrict__ Sm, int sb,
                                        const v2f* tap)
{
  constexpr int S_ = 8 - ((NN<7)?(7-NN):(NN-7));
  constexpr int T0 = (NN>7)?(NN-7):0;
  constexpr int SR = (S_+1)&~1;
#pragma unroll
  for (int o=O0;o<O1;o++){
    v2f acc = cmul_s0(tap[0], *(const v2f*)&gsec[o*SR]);     // inline-0 init
#pragma unroll
    for (int i=1;i<S_;i++)
      cmac_s(acc, tap[i], *(const v2f*)&gsec[o*SR+i]);       // uniform s_load
    *(v2f*)&Sm[sb + koff<PM>(7*(T0+o)+NN)] = acc;
  }
}

template<int PM>
__device__ __forceinline__ void bs_gate(const float2* __restrict__ gb,
                                        float2* __restrict__ Sm, int sb, int wvu)
{
  v2f tap[15];                        // compile-time-indexed -> registers
  // phase A: read taps (state of this gate) into registers
  if (wvu==0){      bs_read<7 ,PM>(Sm,sb,tap);   bs_read<1 ,PM>(Sm,sb,tap+8); }
  else if (wvu==1){ bs_read<7 ,PM>(Sm,sb,tap);   bs_read<4 ,PM>(Sm,sb,tap+8); }
  else if (wvu==2){ bs_read<6 ,PM>(Sm,sb,tap);   bs_read<0 ,PM>(Sm,sb,tap+7); }
  else if (wvu==3){ bs_read<6 ,PM>(Sm,sb,tap);   bs_read<5 ,PM>(Sm,sb,tap+7); }
  else if (wvu==4){ bs_read<8 ,PM>(Sm,sb,tap);   bs_read<14,PM>(Sm,sb,tap+7); }
  else if (wvu==5){ bs_read<8 ,PM>(Sm,sb,tap);   bs_read<9 ,PM>(Sm,sb,tap+7); }
  else if (wvu==6){ bs_read<4 ,PM>(Sm,sb,tap);   bs_read<10,PM>(Sm,sb,tap+5);
                    bs_read<2 ,PM>(Sm,sb,tap+10); bs_read<13,PM>(Sm,sb,tap+13); }
  else {            bs_read<3 ,PM>(Sm,sb,tap);   bs_read<11,PM>(Sm,sb,tap+4);
                    bs_read<12,PM>(Sm,sb,tap+8); }
  __syncthreads();
  // phase B: balanced (sector, output-range) compute + write (disjoint addrs)
  if (wvu==0){      bs_comp<7 ,PM,0,5>(gb+156,Sm,sb,tap);
                    bs_comp<1 ,PM,0,2>(gb+2,  Sm,sb,tap+8); }
  else if (wvu==1){ bs_comp<7 ,PM,5,8>(gb+156,Sm,sb,tap);
                    bs_comp<4 ,PM,0,4>(gb+34, Sm,sb,tap+8); }
  else if (wvu==2){ bs_comp<6 ,PM,0,6>(gb+100,Sm,sb,tap);
                    bs_comp<0 ,PM,0,1>(gb+0,  Sm,sb,tap+7); }
  else if (wvu==3){ bs_comp<6 ,PM,6,7>(gb+100,Sm,sb,tap);
                    bs_comp<5 ,PM,0,6>(gb+64, Sm,sb,tap+7); }
  else if (wvu==4){ bs_comp<8 ,PM,0,6>(gb+220,Sm,sb,tap);
                    bs_comp<14,PM,0,1>(gb+374,Sm,sb,tap+7); }
  else if (wvu==5){ bs_comp<8 ,PM,6,7>(gb+220,Sm,sb,tap);
                    bs_comp<9 ,PM,0,6>(gb+276,Sm,sb,tap+7); }
  else if (wvu==6){ bs_comp<4 ,PM,4,5>(gb+34, Sm,sb,tap);
                    bs_comp<10,PM,0,5>(gb+312,Sm,sb,tap+5);
                    bs_comp<2 ,PM,0,3>(gb+6,  Sm,sb,tap+10);
                    bs_comp<13,PM,0,2>(gb+370,Sm,sb,tap+13); }
  else {            bs_comp<3 ,PM,0,4>(gb+18, Sm,sb,tap);
                    bs_comp<11,PM,0,4>(gb+342,Sm,sb,tap+4);
                    bs_comp<12,PM,0,3>(gb+358,Sm,sb,tap+8); }
  __syncthreads();
}

// one-mode gate on mode M; 1 line per thread (v = t in 0..511), compile-time
// strides -> ds offset immediates; line-exclusive -> single trailing barrier.
template<int M>
__device__ __forceinline__ void one_mode(const float2* __restrict__ gb,
                                         float2* __restrict__ Sm, int t)
{
  constexpr int ek = (M==0)?520:((M==1)?65:((M==2)?8:1));
  const int v = t;
  int base;
  if constexpr (M==0)      base = 65*(v>>6) + 8*((v>>3)&7) + (v&7);
  else if constexpr (M==1) base = 520*(v>>6) + 8*((v>>3)&7) + (v&7);
  else if constexpr (M==2) base = 520*(((v>>3)&1)|(((v>>7)&3)<<1)) + 65*((v>>4)&7) + (v&7);
  else                     base = 520*((v>>4)&7) + 65*(v&7) + 8*(((v>>3)&1)|(((v>>7)&3)<<1));
  v2f acc[8];
#pragma unroll
  for (int k=0;k<8;k++){
    const v2f sA = *(const v2f*)&Sm[base + ek*k];
#pragma unroll
    for (int j=0;j<8;j++){
      const v2f g = *(const v2f*)&gb[k*8+j];      // uniform -> s_load -> SGPR pair
      if (k==0) acc[j] = cmul_s0(sA, g);
      else      cmac_s(acc[j], sA, g);
    }
  }
#pragma unroll
  for (int j=0;j<8;j++) *(v2f*)&Sm[base + ek*j] = acc[j];
  __syncthreads();
}

__global__ __launch_bounds__(512,2) void qnn_main(
    const float* __restrict__ x, const float2* __restrict__ ws,
    float* __restrict__ out)
{
  __shared__ __align__(16) float2 S[4160];     // 4096 + pad(idx>>6)  (33280 B)
  __shared__ float colf[32];
  __shared__ float red[32];
  const int b = blockIdx.x, t = threadIdx.x;   // t in 0..511
  const int lane = t & 63;
  const int wvu = __builtin_amdgcn_readfirstlane(t>>6);   // wave id 0..7
  const int i2c = (t>>3)&7, i3c = t&7;

  // coherent columns: c_n = e^{-x^2/2} x^n / sqrt(n!)
  if (t < 32){
    const int m = t>>3, n = t&7;
    const float xv = x[b*4+m];
    float val = expf(-0.5f*xv*xv);
    for (int q=1;q<=n;q++) val *= xv * rsqrtf((float)q);
    colf[t] = val;
  }
  __syncthreads();
  { // idx = e*512 + t: i0 = e, i1 = wvu, i2 = i2c, i3 = i3c  (thread-exclusive)
    const float c23 = colf[16+i2c]*colf[24+i3c];
    const float c1  = colf[8+wvu];
#pragma unroll
    for (int e=0;e<8;e++){
      const int idx = e*512 + t;
      S[idx + (idx>>6)] = make_float2(colf[e] * c1 * c23, 0.f);
    }
  }
  __syncthreads();

  // spectator bases per pair map (bank-pair-complete per 16-lane phase group)
  const int sbP0 = lane;                               // pair (0,1): spec=(i2,i3)
  const int sbP1 = 520*(lane>>3) + (lane&7);           // pair (1,2): spec=(i0,i3)
  const int sbP2 = 520*(lane>>3) + 65*(lane&7);        // pair (2,3): spec=(i0,i1)
  const float2* ws_g1 = ws + WS_G1_OFF;

#pragma unroll 1
  for (int seg=0; seg<4; seg++){                       // seg = l*2 + r
    const float2* bsg = ws + seg*(6*384);
#pragma unroll 1
    for (int q=0; q<6; q++){                           // pair pattern 0,2,1,0,2,1
      const float2* gq = bsg + q*384;
      const int pm = (q>=3)? (q-3) : q;
      if (pm==0)      bs_gate<0>(gq, S, sbP0, wvu);    // pair (0,1)
      else if (pm==1) bs_gate<2>(gq, S, sbP2, wvu);    // pair (2,3)
      else            bs_gate<1>(gq, S, sbP1, wvu);    // pair (1,2)
    }
    const int l = seg>>1, r = seg&1;
    const float2* om = ws_g1 + (r*8 + l*4)*64;         // r=0: squeeze', r=1: disp'
    one_mode<0>(om,     S, t);
    one_mode<1>(om+64,  S, t);
    one_mode<2>(om+128, S, t);
    one_mode<3>(om+192, S, t);
  }

  // <X_i> = 2 Re sum conj(s[n_i]) sqrt(n_i+1) s[n_i+1]
  // idx = e*512 + t: i0 = e (compile-time), i1 = wvu (wave-uniform)
  const float w1 = sqrtf((float)(wvu+1));
  const float w2 = sqrtf((float)(i2c+1)), w3 = sqrtf((float)(i3c+1));
  float am0=0.f, am1=0.f, am2=0.f, am3=0.f;
#pragma unroll
  for (int e=0;e<8;e++){
    const int idx = e*512 + t;
    const float2 a = S[idx + (idx>>6)];
    if (e < 7){
      const int j2 = idx + 512; const float2 bz = S[j2 + (j2>>6)];
      am0 = fmaf(a.x*bz.x + a.y*bz.y, sqrtf((float)(e+1)), am0);
    }
    if (wvu < 7){
      const int j2 = idx + 64; const float2 bz = S[j2 + (j2>>6)];
      am1 = fmaf(a.x*bz.x + a.y*bz.y, w1, am1);
    }
    if (i2c < 7){
      const int j2 = idx + 8; const float2 bz = S[j2 + (j2>>6)];
      am2 = fmaf(a.x*bz.x + a.y*bz.y, w2, am2);
    }
    if (i3c < 7){
      const int j2 = idx + 1; const float2 bz = S[j2 + (j2>>6)];
      am3 = fmaf(a.x*bz.x + a.y*bz.y, w3, am3);
    }
  }
#pragma unroll
  for (int o=32;o;o>>=1){
    am0 += __shfl_down(am0,o,64);
    am1 += __shfl_down(am1,o,64);
    am2 += __shfl_down(am2,o,64);
    am3 += __shfl_down(am3,o,64);
  }
  __syncthreads();
  if ((t&63)==0){
    red[wvu*4+0]=am0; red[wvu*4+1]=am1; red[wvu*4+2]=am2; red[wvu*4+3]=am3;
  }
  __syncthreads();
  if (t<4){
    float s = 0.f;
#pragma unroll
    for (int w=0;w<8;w++) s += red[w*4+t];
    out[b*4+t] = 2.f*s;
  }
}

// ---------------- host ----------------
extern "C" void kernel_launch(void* const* d_in, const int* in_sizes, int n_in,
                              void* d_out, int out_size, void* d_ws, size_t ws_size,
                              hipStream_t stream)
{
  const float* x    = (const float*)d_in[0];
  const float* th1  = (const float*)d_in[1];
  const float* ph1  = (const float*)d_in[2];
  const float* vph1 = (const float*)d_in[3];
  const float* rr   = (const float*)d_in[4];
  const float* phr  = (const float*)d_in[5];
  const float* th2  = (const float*)d_in[6];
  const float* ph2  = (const float*)d_in[7];
  const float* vph2 = (const float*)d_in[8];
  const float* aa   = (const float*)d_in[9];
  const float* pha  = (const float*)d_in[10];
  const float* kap  = (const float*)d_in[11];
  float2* ws  = (float2*)d_ws;
  float*  out = (float*)d_out;
  const int B = in_sizes[0] / 4;

  hipLaunchKernelGGL(setup_bs, dim3(24), dim3(256), 0, stream, th1, ph1, th2, ph2, ws);
  hipLaunchKernelGGL(setup_small, dim3(16), dim3(128), 0, stream,
                     rr, phr, aa, pha, vph1, vph2, kap, ws + WS_G1_OFF);
  hipLaunchKernelGGL(qnn_main, dim3(B), dim3(512), 0, stream, x, ws, out);
}

// Round 16
// 485.556 us; speedup vs baseline: 1.0992x; 1.0992x over previous
//
#include <hip/hip_runtime.h>
#include <math.h>

// ---------------- workspace layout (float2 units) ----------------
// ws_bs : 24 gates x 384  sector-packed BS: for sector N (size s, row SR=even(s)),
//                         g[SECBASE[N] + o*SR + ti] = U[j_o][k_ti]
// ws_g1 : 16 gates x 64   one-mode GT[k*8+j] with rotation/Kerr diagonals folded
#define WS_G1_OFF   (24*384)

typedef float v2f __attribute__((ext_vector_type(2)));
typedef float v4f __attribute__((ext_vector_type(4)));

// complex MAC, gate in SGPR pair: 2 VALU per cmac, zero movs.
__device__ __forceinline__ void cmac_s(v2f& acc, v2f s, v2f g){
  asm("v_pk_fma_f32 %0, %1, %2, %0 op_sel_hi:[0,1,1]\n\t"
      "v_pk_fma_f32 %0, %1, %2, %0 op_sel:[1,1,0] op_sel_hi:[1,0,1] neg_lo:[1,0,0]"
      : "+v"(acc) : "v"(s), "s"(g));
}
// acc = s*g with inline-0 src2 on the first pk (no v_mov init)
__device__ __forceinline__ v2f cmul_s0(v2f s, v2f g){
  v2f acc;
  asm("v_pk_fma_f32 %0, %1, %2, 0 op_sel_hi:[0,1,1]\n\t"
      "v_pk_fma_f32 %0, %1, %2, %0 op_sel:[1,1,0] op_sel_hi:[1,0,1] neg_lo:[1,0,0]"
      : "=&v"(acc) : "v"(s), "s"(g));
  return acc;
}
// all-VGPR variant for setup kernels (operands not provably uniform)
__device__ __forceinline__ void cmac_v(v2f& acc, v2f s, v2f g){
  asm("v_pk_fma_f32 %0, %1, %2, %0 op_sel_hi:[0,1,1]\n\t"
      "v_pk_fma_f32 %0, %1, %2, %0 op_sel:[1,1,0] op_sel_hi:[1,0,1] neg_lo:[1,0,0]"
      : "+v"(acc) : "v"(s), "v"(g));
}

// ---------------- setup: 24 beamsplitter 64x64 expm ----------------
__global__ __launch_bounds__(256) void setup_bs(
    const float* __restrict__ th1, const float* __restrict__ ph1,
    const float* __restrict__ th2, const float* __restrict__ ph2,
    float2* __restrict__ ws)
{
  __shared__ float2 bufA[4096];
  __shared__ float2 bufB[4096];
  const int g = blockIdx.x;          // 0..23
  const int t = threadIdx.x;
  const int l = g/12, intf = (g%12)/6, pos = g%6;
  const float th = (intf ? th2 : th1)[l*6+pos];
  const float ph = (intf ? ph2 : ph1)[l*6+pos];
  float nrm = fabsf(th)*14.0f;                 // row-sum norm bound
  int sq = 0;
  if (nrm > 2.0f) sq = (int)ceilf(log2f(nrm*0.5f));   // Taylor-12 good to ||H||<=2
  const float tc  = th * ldexpf(1.0f, -sq);    // scaled theta
  const float cph = cosf(ph), sph = sinf(ph);

  float2* cur = bufA; float2* nxt = bufB;
  for (int e=0;e<16;e++){ int idx=e*256+t;
    cur[idx] = make_float2(((idx>>6)==(idx&63))?1.f:0.f, 0.f); }
  __syncthreads();
  // Horner Taylor: B = I + Hs*B/k, k=12..1   (Hs applied sparsely: 2 taps/row)
  for (int k=12;k>=1;k--){
    const float inv = 1.0f/(float)k;
    for (int e=0;e<16;e++){
      const int idx=e*256+t; const int row=idx>>6, c=idx&63;
      const int m1=row>>3, m2=row&7;
      float vx=0.f, vy=0.f;
      if (m1<7 && m2>=1){
        const float mag = tc*sqrtf((float)((m1+1)*m2));
        const float2 q = cur[((m1+1)*8+(m2-1))*64 + c];
        vx += mag*(cph*q.x - sph*q.y);
        vy += mag*(cph*q.y + sph*q.x);
      }
      if (m1>=1 && m2<7){
        const float mag = tc*sqrtf((float)(m1*(m2+1)));
        const float2 q = cur[((m1-1)*8+(m2+1))*64 + c];
        vx -= mag*(cph*q.x + sph*q.y);
        vy -= mag*(cph*q.y - sph*q.x);
      }
      vx *= inv; vy *= inv;
      if (row==c) vx += 1.0f;
      nxt[idx] = make_float2(vx,vy);
    }
    __syncthreads();
    float2* tmp=cur; cur=nxt; nxt=tmp;
  }
  // squarings: pk_fma pairs, broadcast A row, conflict-free B column
  for (int si=0; si<sq; si++){
    for (int e=0;e<16;e++){
      const int idx=e*256+t; const int row=idx>>6, c=idx&63;
      const float2* Arow = cur + row*64;
      v2f acc = (v2f){0.f,0.f};
      for (int q=0;q<64;q+=2){
        const v4f ap = *(const v4f*)&Arow[q];
        const v2f b0 = *(const v2f*)&cur[q*64+c];
        const v2f b1 = *(const v2f*)&cur[(q+1)*64+c];
        cmac_v(acc, b0, (v2f){ap.x,ap.y});
        cmac_v(acc, b1, (v2f){ap.z,ap.w});
      }
      nxt[idx] = make_float2(acc.x, acc.y);
    }
    __syncthreads();
    float2* tmp=cur; cur=nxt; nxt=tmp;
  }
  // sector-packed write: enumerate (N, o, ti-with-row-pad) linearly over 384 slots
  for (int e=t; e<384; e+=256){
    int rem = e, N = 0, S_=0, SR_=0;
    for (; N<15; N++){
      S_  = 8 - ((N<7)?(7-N):(N-7));
      SR_ = (S_+1)&~1;
      if (rem < S_*SR_) break;
      rem -= S_*SR_;
    }
    float2 v = make_float2(0.f,0.f);
    if (N < 15){
      const int o = rem / SR_, ti = rem % SR_;
      if (ti < S_){
        const int T0 = (N>7)?(N-7):0;
        const int j = 7*(T0+o)+N, k = 7*(T0+ti)+N;
        v = cur[j*64 + k];
      }
    }
    ws[g*384 + e] = v;
  }
}

// ---------------- setup: 16 one-mode 8x8 expm, diagonals folded in ----------------
__global__ __launch_bounds__(128) void setup_small(
    const float* __restrict__ rr,  const float* __restrict__ phr,
    const float* __restrict__ aa,  const float* __restrict__ pha,
    const float* __restrict__ vph1,const float* __restrict__ vph2,
    const float* __restrict__ kap,
    float2* __restrict__ ws_g1)
{
  const int g = blockIdx.x, t = threadIdx.x;   // g: 0..15
  __shared__ float2 h8[64], bufA[64], bufB[64];
  const int isSq = (g < 8);
  const int gi = isSq ? g : (g-8);
  const int li = gi>>2, m = gi&3;
  const float p1 = isSq ? rr[li*4+m]  : aa[li*4+m];
  const float p2 = isSq ? phr[li*4+m] : pha[li*4+m];
  const float nrm = fabsf(p1)*6.0f;
  int sq = 0; if (nrm > 2.0f) sq = (int)ceilf(log2f(nrm*0.5f));
  const float sc = ldexpf(1.0f,-sq);
  const float cp = cosf(p2), sp = sinf(p2);
  if (t < 64){
    const int row=t>>3, c=t&7;
    float2 v = make_float2(0.f,0.f);
    if (isSq){
      if (c == row+2){ const float mg = 0.5f*p1*sqrtf((float)((row+1)*(row+2)));
                       v = make_float2( mg*cp, -mg*sp); }
      else if (c+2 == row){ const float mg = 0.5f*p1*sqrtf((float)((row-1)*row));
                       v = make_float2(-mg*cp, -mg*sp); }
    } else {
      if (c+1 == row){ const float mg = p1*sqrtf((float)row);
                       v = make_float2( mg*cp,  mg*sp); }
      else if (c == row+1){ const float mg = p1*sqrtf((float)(row+1));
                       v = make_float2(-mg*cp,  mg*sp); }
    }
    h8[t]   = make_float2(v.x*sc, v.y*sc);
    bufA[t] = make_float2((row==c)?1.f:0.f, 0.f);
  }
  __syncthreads();
  float2* cur=bufA; float2* nxt=bufB;
  for (int k=12;k>=1;k--){
    const float inv = 1.0f/(float)k;
    if (t<64){
      const int row=t>>3, c=t&7;
      float vx=0.f, vy=0.f;
      for (int q=0;q<8;q++){
        const float2 a_=h8[row*8+q], b_=cur[q*8+c];
        vx += a_.x*b_.x - a_.y*b_.y; vy += a_.x*b_.y + a_.y*b_.x;
      }
      vx*=inv; vy*=inv; if (row==c) vx += 1.f;
      nxt[t]=make_float2(vx,vy);
    }
    __syncthreads();
    float2* tmp=cur; cur=nxt; nxt=tmp;
  }
  for (int si=0; si<sq; si++){
    if (t<64){
      const int row=t>>3, c=t&7;
      float vx=0.f, vy=0.f;
      for (int q=0;q<8;q++){
        const float2 a_=cur[row*8+q], b_=cur[q*8+c];
        vx += a_.x*b_.x - a_.y*b_.y; vy += a_.x*b_.y + a_.y*b_.x;
      }
      nxt[t]=make_float2(vx,vy);
    }
    __syncthreads();
    float2* tmp=cur; cur=nxt; nxt=tmp;
  }
  if (t<64){
    const int kk=t>>3, j=t&7;
    const float2 v = cur[j*8+kk];          // G[j][kk]
    float ang;
    if (isSq) ang = vph1[li*4+m]*(float)kk;
    else      ang = vph2[li*4+m]*(float)kk + kap[li*4+m]*(float)(j*j);
    const float ca = cosf(ang), sa = sinf(ang);
    ws_g1[g*64 + t] = make_float2(v.x*ca - v.y*sa, v.x*sa + v.y*ca);  // GT[k][j]
  }
}

// ---------------- main kernel: 512 threads (8 waves), 4 blocks/CU ----------------
// State in LDS, padded: addr(idx) = idx + (idx>>6) -> strides i0:520 i1:65 i2:8 i3:1.
// LDS total 33792 B -> exactly 4 blocks/CU (5 blocks/CU triggers phantom HBM
// traffic: R3/R10/R13 all dirty at 5 blocks; every 4- or 2-block build clean).
// 8 waves give 32 waves/CU = full occupancy for latency hiding.
// bs_gate: lane = spectator (64 lanes); 8 waves own disjoint photon-number sectors
// (single trailing barrier; R15's balanced two-phase variant regressed -25%).
// Gates: uniform s_load -> SGPR pair folded into v_pk_fma (2 VALU/cmac).

// padded tap offset for combined pair index k within each pair map
template<int PM>
__device__ __forceinline__ constexpr int koff(int k){
  return (PM==0) ? 65*k : ((PM==1) ? (8*k + (k>>3)) : k);
}

template<int NN,int PM>
__device__ __forceinline__ void bs_sector(const float2* __restrict__ gsec,
                                          float2* __restrict__ Sm, int sb)
{
  constexpr int S_ = 8 - ((NN<7)?(7-NN):(NN-7));
  constexpr int T0 = (NN>7)?(NN-7):0;
  constexpr int SR = (S_+1)&~1;
  v2f sv[S_];
#pragma unroll
  for (int i=0;i<S_;i++)
    sv[i] = *(const v2f*)&Sm[sb + koff<PM>(7*(T0+i)+NN)];   // offset:imm
#pragma unroll
  for (int o=0;o<S_;o++){
    v2f acc = cmul_s0(sv[0], *(const v2f*)&gsec[o*SR]);     // inline-0 init
#pragma unroll
    for (int i=1;i<S_;i++)
      cmac_s(acc, sv[i], *(const v2f*)&gsec[o*SR+i]);       // uniform s_load
    *(v2f*)&Sm[sb + koff<PM>(7*(T0+o)+NN)] = acc;
  }
}

template<int PM>
__device__ __forceinline__ void bs_gate(const float2* __restrict__ gb,
                                        float2* __restrict__ Sm, int sb, int wvu)
{
  // 8-wave sector bins (cmac loads: 64/50/50/40/40/34/34/32)
  if (wvu==0){
    bs_sector<7 ,PM>(gb+156, Sm, sb);
  } else if (wvu==1){
    bs_sector<6 ,PM>(gb+100, Sm, sb);
    bs_sector<14,PM>(gb+374, Sm, sb);
  } else if (wvu==2){
    bs_sector<8 ,PM>(gb+220, Sm, sb);
    bs_sector<0 ,PM>(gb+0,   Sm, sb);
  } else if (wvu==3){
    bs_sector<5 ,PM>(gb+64,  Sm, sb);
    bs_sector<13,PM>(gb+370, Sm, sb);
  } else if (wvu==4){
    bs_sector<9 ,PM>(gb+276, Sm, sb);
    bs_sector<1 ,PM>(gb+2,   Sm, sb);
  } else if (wvu==5){
    bs_sector<4 ,PM>(gb+34,  Sm, sb);
    bs_sector<12,PM>(gb+358, Sm, sb);
  } else if (wvu==6){
    bs_sector<10,PM>(gb+312, Sm, sb);
    bs_sector<2 ,PM>(gb+6,   Sm, sb);
  } else {
    bs_sector<3 ,PM>(gb+18,  Sm, sb);
    bs_sector<11,PM>(gb+342, Sm, sb);
  }
  __syncthreads();
}

// one-mode gate on mode M; 1 line per thread (v = t in 0..511), compile-time
// strides -> ds offset immediates; line-exclusive -> single trailing barrier.
template<int M>
__device__ __forceinline__ void one_mode(const float2* __restrict__ gb,
                                         float2* __restrict__ Sm, int t)
{
  constexpr int ek = (M==0)?520:((M==1)?65:((M==2)?8:1));
  const int v = t;
  int base;
  if constexpr (M==0)      base = 65*(v>>6) + 8*((v>>3)&7) + (v&7);
  else if constexpr (M==1) base = 520*(v>>6) + 8*((v>>3)&7) + (v&7);
  else if constexpr (M==2) base = 520*(((v>>3)&1)|(((v>>7)&3)<<1)) + 65*((v>>4)&7) + (v&7);
  else                     base = 520*((v>>4)&7) + 65*(v&7) + 8*(((v>>3)&1)|(((v>>7)&3)<<1));
  v2f acc[8];
#pragma unroll
  for (int k=0;k<8;k++){
    const v2f sA = *(const v2f*)&Sm[base + ek*k];
#pragma unroll
    for (int j=0;j<8;j++){
      const v2f g = *(const v2f*)&gb[k*8+j];      // uniform -> s_load -> SGPR pair
      if (k==0) acc[j] = cmul_s0(sA, g);
      else      cmac_s(acc[j], sA, g);
    }
  }
#pragma unroll
  for (int j=0;j<8;j++) *(v2f*)&Sm[base + ek*j] = acc[j];
  __syncthreads();
}

__global__ __launch_bounds__(512,2) void qnn_main(
    const float* __restrict__ x, const float2* __restrict__ ws,
    float* __restrict__ out)
{
  __shared__ __align__(16) float2 S[4160];     // 4096 + pad(idx>>6)  (33280 B)
  __shared__ float colf[32];
  __shared__ float red[32];
  const int b = blockIdx.x, t = threadIdx.x;   // t in 0..511
  const int lane = t & 63;
  const int wvu = __builtin_amdgcn_readfirstlane(t>>6);   // wave id 0..7
  const int i2c = (t>>3)&7, i3c = t&7;

  // coherent columns: c_n = e^{-x^2/2} x^n / sqrt(n!)
  if (t < 32){
    const int m = t>>3, n = t&7;
    const float xv = x[b*4+m];
    float val = expf(-0.5f*xv*xv);
    for (int q=1;q<=n;q++) val *= xv * rsqrtf((float)q);
    colf[t] = val;
  }
  __syncthreads();
  { // idx = e*512 + t: i0 = e, i1 = wvu, i2 = i2c, i3 = i3c  (thread-exclusive)
    const float c23 = colf[16+i2c]*colf[24+i3c];
    const float c1  = colf[8+wvu];
#pragma unroll
    for (int e=0;e<8;e++){
      const int idx = e*512 + t;
      S[idx + (idx>>6)] = make_float2(colf[e] * c1 * c23, 0.f);
    }
  }
  __syncthreads();

  // spectator bases per pair map (bank-pair-complete per 16-lane phase group)
  const int sbP0 = lane;                               // pair (0,1): spec=(i2,i3)
  const int sbP1 = 520*(lane>>3) + (lane&7);           // pair (1,2): spec=(i0,i3)
  const int sbP2 = 520*(lane>>3) + 65*(lane&7);        // pair (2,3): spec=(i0,i1)
  const float2* ws_g1 = ws + WS_G1_OFF;

#pragma unroll 1
  for (int seg=0; seg<4; seg++){                       // seg = l*2 + r
    const float2* bsg = ws + seg*(6*384);
#pragma unroll 1
    for (int q=0; q<6; q++){                           // pair pattern 0,2,1,0,2,1
      const float2* gq = bsg + q*384;
      const int pm = (q>=3)? (q-3) : q;
      if (pm==0)      bs_gate<0>(gq, S, sbP0, wvu);    // pair (0,1)
      else if (pm==1) bs_gate<2>(gq, S, sbP2, wvu);    // pair (2,3)
      else            bs_gate<1>(gq, S, sbP1, wvu);    // pair (1,2)
    }
    const int l = seg>>1, r = seg&1;
    const float2* om = ws_g1 + (r*8 + l*4)*64;         // r=0: squeeze', r=1: disp'
    one_mode<0>(om,     S, t);
    one_mode<1>(om+64,  S, t);
    one_mode<2>(om+128, S, t);
    one_mode<3>(om+192, S, t);
  }

  // <X_i> = 2 Re sum conj(s[n_i]) sqrt(n_i+1) s[n_i+1]
  // idx = e*512 + t: i0 = e (compile-time), i1 = wvu (wave-uniform)
  const float w1 = sqrtf((float)(wvu+1));
  const float w2 = sqrtf((float)(i2c+1)), w3 = sqrtf((float)(i3c+1));
  float am0=0.f, am1=0.f, am2=0.f, am3=0.f;
#pragma unroll
  for (int e=0;e<8;e++){
    const int idx = e*512 + t;
    const float2 a = S[idx + (idx>>6)];
    if (e < 7){
      const int j2 = idx + 512; const float2 bz = S[j2 + (j2>>6)];
      am0 = fmaf(a.x*bz.x + a.y*bz.y, sqrtf((float)(e+1)), am0);
    }
    if (wvu < 7){
      const int j2 = idx + 64; const float2 bz = S[j2 + (j2>>6)];
      am1 = fmaf(a.x*bz.x + a.y*bz.y, w1, am1);
    }
    if (i2c < 7){
      const int j2 = idx + 8; const float2 bz = S[j2 + (j2>>6)];
      am2 = fmaf(a.x*bz.x + a.y*bz.y, w2, am2);
    }
    if (i3c < 7){
      const int j2 = idx + 1; const float2 bz = S[j2 + (j2>>6)];
      am3 = fmaf(a.x*bz.x + a.y*bz.y, w3, am3);
    }
  }
#pragma unroll
  for (int o=32;o;o>>=1){
    am0 += __shfl_down(am0,o,64);
    am1 += __shfl_down(am1,o,64);
    am2 += __shfl_down(am2,o,64);
    am3 += __shfl_down(am3,o,64);
  }
  __syncthreads();
  if ((t&63)==0){
    red[wvu*4+0]=am0; red[wvu*4+1]=am1; red[wvu*4+2]=am2; red[wvu*4+3]=am3;
  }
  __syncthreads();
  if (t<4){
    float s = 0.f;
#pragma unroll
    for (int w=0;w<8;w++) s += red[w*4+t];
    out[b*4+t] = 2.f*s;
  }
}

// ---------------- host ----------------
extern "C" void kernel_launch(void* const* d_in, const int* in_sizes, int n_in,
                              void* d_out, int out_size, void* d_ws, size_t ws_size,
                              hipStream_t stream)
{
  const float* x    = (const float*)d_in[0];
  const float* th1  = (const float*)d_in[1];
  const float* ph1  = (const float*)d_in[2];
  const float* vph1 = (const float*)d_in[3];
  const float* rr   = (const float*)d_in[4];
  const float* phr  = (const float*)d_in[5];
  const float* th2  = (const float*)d_in[6];
  const float* ph2  = (const float*)d_in[7];
  const float* vph2 = (const float*)d_in[8];
  const float* aa   = (const float*)d_in[9];
  const float* pha  = (const float*)d_in[10];
  const float* kap  = (const float*)d_in[11];
  float2* ws  = (float2*)d_ws;
  float*  out = (float*)d_out;
  const int B = in_sizes[0] / 4;

  hipLaunchKernelGGL(setup_bs, dim3(24), dim3(256), 0, stream, th1, ph1, th2, ph2, ws);
  hipLaunchKernelGGL(setup_small, dim3(16), dim3(128), 0, stream,
                     rr, phr, aa, pha, vph1, vph2, kap, ws + WS_G1_OFF);
  hipLaunchKernelGGL(qnn_main, dim3(B), dim3(512), 0, stream, x, ws, out);
}